// Round 5
// baseline (33705.066 us; speedup 1.0000x reference)
//
#include <hip/hip_runtime.h>
#include <hip/hip_bf16.h>

#define TT 512
#define BB 256
#define INS 128
#define HH 256
#define SP1 129
#define NB 4            // batches per block
#define NBLK (BB / NB)  // 64 blocks, one per 4 batches

__device__ __forceinline__ float sigmoidf_(float v) { return 1.0f / (1.0f + expf(-v)); }

// pts[t][b] = cumsum of ops[0..t][b]  (ops[0]==0)
__global__ void k_pts(const int* __restrict__ ops, int* __restrict__ pts) {
    int b = threadIdx.x;
    int acc = 0;
#pragma unroll 4
    for (int t = 0; t < TT; ++t) {
        acc += ops[t * BB + b];
        pts[t * BB + b] = acc;
    }
}

// Per-batch stacks, layout [batch][level][h].  Only level 0 (h0/c0) and
// level 128 (the (pt-1)%129 wrap target, read as zeros until legitimately
// written) need initialization: stack discipline writes every other level
// before it is ever read.
__global__ void k_init(const float* __restrict__ h0, const float* __restrict__ c0,
                       float* __restrict__ hS, float* __restrict__ cS) {
    int b = blockIdx.x;      // batch
    int h = threadIdx.x;     // h-unit
    size_t base = (size_t)b * SP1 * HH;
    hS[base + h] = h0[h];
    cS[base + h] = c0[h];
    hS[base + (size_t)(SP1 - 1) * HH + h] = 0.f;
    cS[base + (size_t)(SP1 - 1) * HH + h] = 0.f;
}

__global__ __launch_bounds__(256)
void k_main(const float* __restrict__ x, const int* __restrict__ ops,
            const float* __restrict__ wxi, const float* __restrict__ bi,
            const float* __restrict__ whi, const float* __restrict__ wci,
            const float* __restrict__ wxf, const float* __restrict__ bfp,
            const float* __restrict__ whf, const float* __restrict__ wcf,
            const float* __restrict__ wxc, const float* __restrict__ bcp,
            const float* __restrict__ wxo, const float* __restrict__ bop,
            const float* __restrict__ who, const float* __restrict__ wco,
            float* __restrict__ hS, float* __restrict__ cS,
            const int* __restrict__ pts,
            float* __restrict__ out)
{
    const int tid = threadIdx.x;     // = h-unit hg
    const int blk = blockIdx.x;
    const int bg0 = blk * NB;

    __shared__ float sh[NB][HH];     // cur_h per batch (broadcast reads -> no conflicts)
    __shared__ float sc[NB][HH];     // cur_c per batch
    __shared__ float sx[NB][INS];    // x row per batch

    const float bi_ = bi[tid], bf_ = bfp[tid], bc_ = bcp[tid], bo_ = bop[tid];
    const float* wxi_r = wxi + tid * INS;
    const float* wxf_r = wxf + tid * INS;
    const float* wxc_r = wxc + tid * INS;
    const float* wxo_r = wxo + tid * INS;
    const float* whi_r = whi + tid * HH;
    const float* whf_r = whf + tid * HH;
    const float* who_r = who + tid * HH;
    const float* wci_r = wci + tid * HH;
    const float* wcf_r = wcf + tid * HH;
    const float* wco_r = wco + tid * HH;

    for (int t = 0; t < TT; ++t) {
        const int tB = t * BB;

        // ---- stage: gather cur_h/cur_c/x/prev for the block's 4 batches ----
        int   ptv[NB];
        int   opv[NB];
        float prevv[NB];
#pragma unroll
        for (int nb = 0; nb < NB; ++nb) {
            const int bg = bg0 + nb;
            const int ptn = pts[tB + bg];           // uniform -> scalar load
            ptv[nb] = ptn;
            opv[nb] = ops[(t + 1) * BB + bg];       // uniform -> scalar load
            const size_t sb = (size_t)bg * SP1 * HH;
            sh[nb][tid] = hS[sb + (size_t)ptn * HH + tid];
            sc[nb][tid] = cS[sb + (size_t)ptn * HH + tid];
            const int pm = (ptn == 0) ? (SP1 - 1) : (ptn - 1);
            prevv[nb] = hS[sb + (size_t)pm * HH + tid];
            if (tid < INS) sx[nb][tid] = x[((size_t)tB + bg) * INS + tid];
        }
        __syncthreads();

        // ---- compute: each thread = one h-unit, NB batches ----
        float a_i[NB], a_f[NB], a_hf[NB], a_o[NB], a_c[NB];
#pragma unroll
        for (int nb = 0; nb < NB; ++nb) {
            a_i[nb] = bi_; a_f[nb] = bf_; a_o[nb] = bo_;
            a_c[nb] = bc_; a_hf[nb] = 0.f;
        }

        // x-projections: K = 128, weight float4 reused across 4 batches
#pragma unroll 4
        for (int k = 0; k < INS; k += 4) {
            const float4 wi = *(const float4*)(wxi_r + k);
            const float4 wf = *(const float4*)(wxf_r + k);
            const float4 wc = *(const float4*)(wxc_r + k);
            const float4 wo = *(const float4*)(wxo_r + k);
#pragma unroll
            for (int nb = 0; nb < NB; ++nb) {
                const float4 xv = *(const float4*)&sx[nb][k];
                a_i[nb] += xv.x*wi.x + xv.y*wi.y + xv.z*wi.z + xv.w*wi.w;
                a_f[nb] += xv.x*wf.x + xv.y*wf.y + xv.z*wf.z + xv.w*wf.w;
                a_c[nb] += xv.x*wc.x + xv.y*wc.y + xv.z*wc.z + xv.w*wc.w;
                a_o[nb] += xv.x*wo.x + xv.y*wo.y + xv.z*wo.z + xv.w*wo.w;
            }
        }

        // h/c-projections: K = 256
#pragma unroll 2
        for (int k = 0; k < HH; k += 4) {
            const float4 whiv = *(const float4*)(whi_r + k);
            const float4 wciv = *(const float4*)(wci_r + k);
            const float4 whfv = *(const float4*)(whf_r + k);
            const float4 wcfv = *(const float4*)(wcf_r + k);
            const float4 whov = *(const float4*)(who_r + k);
            const float4 wcov = *(const float4*)(wco_r + k);
#pragma unroll
            for (int nb = 0; nb < NB; ++nb) {
                const float4 hv = *(const float4*)&sh[nb][k];
                const float4 cv = *(const float4*)&sc[nb][k];
                a_i[nb]  += hv.x*whiv.x + hv.y*whiv.y + hv.z*whiv.z + hv.w*whiv.w;
                a_i[nb]  += cv.x*wciv.x + cv.y*wciv.y + cv.z*wciv.z + cv.w*wciv.w;
                a_hf[nb] += hv.x*whfv.x + hv.y*whfv.y + hv.z*whfv.z + hv.w*whfv.w;
                a_f[nb]  += cv.x*wcfv.x + cv.y*wcfv.y + cv.z*wcfv.z + cv.w*wcfv.w;
                a_o[nb]  += hv.x*whov.x + hv.y*whov.y + hv.z*whov.z + hv.w*whov.w;
                a_o[nb]  += cv.x*wcov.x + cv.y*wcov.y + cv.z*wcov.z + cv.w*wcov.w;
            }
        }

        // ---- gates, stack write, output ----
#pragma unroll
        for (int nb = 0; nb < NB; ++nb) {
            const int bg = bg0 + nb;
            const float ig = sigmoidf_(a_i[nb]);
            const float fg = sigmoidf_(a_f[nb] + a_hf[nb]);
            const float og = sigmoidf_(a_o[nb]);
            const float curc = sc[nb][tid];
            const float cg = fg * curc + ig * tanhf(a_c[nb] + a_hf[nb]); // w_hf reuse, per ref
            const float nh = og * tanhf(cg);

            const size_t sb = (size_t)bg * SP1 * HH;
            const size_t wl = sb + (size_t)(ptv[nb] + 1) * HH + tid;
            hS[wl] = nh;
            cS[wl] = cg;
            out[((size_t)tB + bg) * HH + tid] = (opv[nb] > 0) ? nh : prevv[nb];
        }
        __syncthreads();   // stack writes visible (L1, same CU) before next stage
    }
}

extern "C" void kernel_launch(void* const* d_in, const int* in_sizes, int n_in,
                              void* d_out, int out_size, void* d_ws, size_t ws_size,
                              hipStream_t stream) {
    const float* x   = (const float*)d_in[0];
    const int*   ops = (const int*)d_in[1];
    const float* wxi = (const float*)d_in[2];
    const float* bi  = (const float*)d_in[3];
    const float* whi = (const float*)d_in[4];
    const float* wci = (const float*)d_in[5];
    const float* wxf = (const float*)d_in[6];
    const float* bf  = (const float*)d_in[7];
    const float* whf = (const float*)d_in[8];
    const float* wcf = (const float*)d_in[9];
    const float* wxc = (const float*)d_in[10];
    const float* bc  = (const float*)d_in[11];
    const float* wxo = (const float*)d_in[12];
    const float* bo  = (const float*)d_in[13];
    const float* who = (const float*)d_in[14];
    const float* wco = (const float*)d_in[15];
    const float* h0  = (const float*)d_in[16];
    const float* c0  = (const float*)d_in[17];
    float* out = (float*)d_out;

    // ws layout: hS [256][129][256] f32, cS same, pts [512][256] i32
    const size_t stackElems = (size_t)BB * SP1 * HH;   // 8,454,144 floats
    float* hS  = (float*)d_ws;
    float* cS  = hS + stackElems;
    int*   pts = (int*)(cS + stackElems);
    size_t need = (size_t)((char*)(pts + (size_t)TT * BB) - (char*)d_ws);
    if (ws_size < need) return;

    k_pts<<<1, 256, 0, stream>>>(ops, pts);
    k_init<<<BB, HH, 0, stream>>>(h0, c0, hS, cS);
    k_main<<<NBLK, 256, 0, stream>>>(x, ops, wxi, bi, whi, wci, wxf, bf, whf, wcf,
                                     wxc, bc, wxo, bo, who, wco,
                                     hS, cS, pts, out);
}

// Round 8
// 7492.215 us; speedup vs baseline: 4.4987x; 4.4987x over previous
//
#include <hip/hip_runtime.h>
#include <hip/hip_bf16.h>

#define TT 512
#define BB 256
#define INS 128
#define HH 256
#define SP1 129
#define NBLK 256
#define FLAG_STRIDE 64   // 64 uints = 256B per flag slot

// LDS float layout: w_lds [0,32768) | sh [32768,36864) | sc [36864,40960)
// = 163,840 bytes exactly (gfx950 max workgroup LDS).
// w_lds: 16 rows x 2048 floats. Row float-offsets:
//   whi@0 wci@256 whf@512 wcf@768 who@1024 wco@1280 | wxi@1536 wxf@1664 wxc@1792 wxo@1920
// All arrays granule(16B)-XOR-swizzled: phys_granule = logical_granule ^ (row&7).
// Segment bases are multiples of 32 granules, so base ^ stays intact.

__device__ __forceinline__ float sigmoidf_(float v) { return 1.0f / (1.0f + expf(-v)); }

__device__ __forceinline__ float ld_coh(const float* p) {
    return __hip_atomic_load(p, __ATOMIC_RELAXED, __HIP_MEMORY_SCOPE_SYSTEM);
}
__device__ __forceinline__ void st_coh(float* p, float v) {
    __hip_atomic_store(p, v, __ATOMIC_RELAXED, __HIP_MEMORY_SCOPE_SYSTEM);
}

__global__ void k_pts(const int* __restrict__ ops, int* __restrict__ pts) {
    int b = threadIdx.x;
    int acc = 0;
#pragma unroll 4
    for (int t = 0; t < TT; ++t) {
        acc += ops[t * BB + b];
        pts[t * BB + b] = acc;
    }
}

// stacks layout [level][batch][h]; init level 0 = h0/c0, level 128 = 0
// (levels 1..127 are always written before read by stack discipline)
__global__ void k_init(const float* __restrict__ h0, const float* __restrict__ c0,
                       float* __restrict__ hS, float* __restrict__ cS) {
    int b = blockIdx.x, h = threadIdx.x;
    hS[(size_t)b * HH + h] = h0[h];
    cS[(size_t)b * HH + h] = c0[h];
    size_t l128 = ((size_t)(SP1 - 1) * BB + b) * HH + h;
    hS[l128] = 0.f;
    cS[l128] = 0.f;
}

__device__ __forceinline__ void stage_seg(float* w_lds, const float* src, int hbase,
                                          int L, int off4, int tid) {
    // L=256: 1024 float4s (64/row); L=128: 512 float4s (32/row)
    const int per_row = L >> 2;
    const int total = per_row * 16;
    for (int idx = tid; idx < total; idx += 256) {
        int row = idx / per_row;
        int g   = idx - row * per_row;
        float4 v = *(const float4*)(src + (size_t)(hbase + row) * L + g * 4);
        int P = off4 + (g ^ (row & 7));
        *(float4*)(w_lds + row * 2048 + P * 4) = v;
    }
}

__global__ __launch_bounds__(256)
void k_main(const float* __restrict__ x, const int* __restrict__ ops,
            const float* __restrict__ wxi, const float* __restrict__ bi,
            const float* __restrict__ whi, const float* __restrict__ wci,
            const float* __restrict__ wxf, const float* __restrict__ bfp,
            const float* __restrict__ whf, const float* __restrict__ wcf,
            const float* __restrict__ wxc, const float* __restrict__ bcp,
            const float* __restrict__ wxo, const float* __restrict__ bop,
            const float* __restrict__ who, const float* __restrict__ wco,
            float* __restrict__ hS, float* __restrict__ cS,
            const int* __restrict__ pts, unsigned* __restrict__ flags,
            float* __restrict__ out)
{
    extern __shared__ float lds[];
    float* w_lds  = lds;            // 32768 floats
    float* sh_lds = lds + 32768;    // 4096 floats
    float* sc_lds = lds + 36864;    // 4096 floats

    const int tid   = threadIdx.x;
    const int blk   = blockIdx.x;
    const int btile = blk >> 4;     // 16 blocks share a btile (flag group)
    const int htile = blk & 15;
    const int hl = tid & 15, bl = tid >> 4;
    const int hg = htile * 16 + hl;          // global h unit (this thread's output row)
    const int bg = btile * 16 + bl;          // global batch
    const int wv = tid >> 6;
    const int ln = tid & 63;
    const int s  = hl & 7;                   // weight-row swizzle key
    const int sb = bl & 7;                   // h/c-row swizzle key
    const int hbase = htile * 16;

    // ---- one-time: stage this h-tile's 10 weight slices into LDS ----
    stage_seg(w_lds, whi, hbase, 256, 0,   tid);
    stage_seg(w_lds, wci, hbase, 256, 64,  tid);
    stage_seg(w_lds, whf, hbase, 256, 128, tid);
    stage_seg(w_lds, wcf, hbase, 256, 192, tid);
    stage_seg(w_lds, who, hbase, 256, 256, tid);
    stage_seg(w_lds, wco, hbase, 256, 320, tid);
    stage_seg(w_lds, wxi, hbase, 128, 384, tid);
    stage_seg(w_lds, wxf, hbase, 128, 416, tid);
    stage_seg(w_lds, wxc, hbase, 128, 448, tid);
    stage_seg(w_lds, wxo, hbase, 128, 480, tid);
    __syncthreads();

    const float bi_ = bi[hg], bf_ = bfp[hg], bc_ = bcp[hg], bo_ = bop[hg];
    const float* wrow  = w_lds + hl * 2048;
    const float* shrow = sh_lds + bl * 256;
    const float* scrow = sc_lds + bl * 256;
    unsigned* grpflags = flags + (size_t)btile * 16 * FLAG_STRIDE;

    for (int t = 0; t < TT; ++t) {
        const int tB = t * BB;

        // ---- Phase A: x-projections (independent of other blocks) ----
        float xa_i = bi_, xa_f = bf_, xa_c = bc_, xa_o = bo_;
        {
            const float* xrow = x + ((size_t)tB + bg) * INS;
#pragma unroll 2
            for (int g = 0; g < 32; ++g) {
                const float4 xv = *(const float4*)(xrow + g * 4);
                const float* wp = wrow + ((g ^ s) << 2);
                float4 w;
                w = *(const float4*)(wp + 1536); xa_i += xv.x*w.x + xv.y*w.y + xv.z*w.z + xv.w*w.w;
                w = *(const float4*)(wp + 1664); xa_f += xv.x*w.x + xv.y*w.y + xv.z*w.z + xv.w*w.w;
                w = *(const float4*)(wp + 1792); xa_c += xv.x*w.x + xv.y*w.y + xv.z*w.z + xv.w*w.w;
                w = *(const float4*)(wp + 1920); xa_o += xv.x*w.x + xv.y*w.y + xv.z*w.z + xv.w*w.w;
            }
        }
        const int pt = pts[tB + bg];
        const int op = ops[(t + 1) * BB + bg];

        // ---- Phase B: wait for the 16 group members to finish step t-1 ----
        if (tid < 16) {
            unsigned* f = grpflags + tid * FLAG_STRIDE;
            const unsigned want = (unsigned)t;
            while (__hip_atomic_load(f, __ATOMIC_RELAXED, __HIP_MEMORY_SCOPE_AGENT) < want)
                __builtin_amdgcn_s_sleep(1);
        }
        __syncthreads();

        // ---- Phase C: gather cur_h/cur_c (UC) into swizzled LDS ----
#pragma unroll
        for (int r = 0; r < 4; ++r) {
            const int rr  = wv * 4 + r;
            const int bgr = btile * 16 + rr;
            const int ptn = pts[tB + bgr];
            const float* hb = hS + ((size_t)ptn * BB + bgr) * HH + 4 * ln;
            const float* cb = cS + ((size_t)ptn * BB + bgr) * HH + 4 * ln;
            float h0v = ld_coh(hb + 0), h1v = ld_coh(hb + 1),
                  h2v = ld_coh(hb + 2), h3v = ld_coh(hb + 3);
            float c0v = ld_coh(cb + 0), c1v = ld_coh(cb + 1),
                  c2v = ld_coh(cb + 2), c3v = ld_coh(cb + 3);
            const int pg = ln ^ (rr & 7);
            *(float4*)(sh_lds + rr * 256 + pg * 4) = make_float4(h0v, h1v, h2v, h3v);
            *(float4*)(sc_lds + rr * 256 + pg * 4) = make_float4(c0v, c1v, c2v, c3v);
        }
        float prev = 0.f;
        if (op <= 0) {
            int pm = (pt == 0) ? (SP1 - 1) : (pt - 1);
            prev = ld_coh(hS + ((size_t)pm * BB + bg) * HH + hg);
        }
        __syncthreads();

        // ---- Phase D: 6 K=256 dots, all operands in LDS ----
        float a_i = xa_i, a_f = xa_f, a_o = xa_o, a_hf = 0.f;
#pragma unroll 2
        for (int g = 0; g < 64; ++g) {
            const int gb = (g ^ sb) << 2;
            const float4 hv = *(const float4*)(shrow + gb);
            const float4 cv = *(const float4*)(scrow + gb);
            const float* wp = wrow + ((g ^ s) << 2);
            float4 w;
            w = *(const float4*)(wp + 0);    a_i  += hv.x*w.x + hv.y*w.y + hv.z*w.z + hv.w*w.w;
            w = *(const float4*)(wp + 256);  a_i  += cv.x*w.x + cv.y*w.y + cv.z*w.z + cv.w*w.w;
            w = *(const float4*)(wp + 512);  a_hf += hv.x*w.x + hv.y*w.y + hv.z*w.z + hv.w*w.w;
            w = *(const float4*)(wp + 768);  a_f  += cv.x*w.x + cv.y*w.y + cv.z*w.z + cv.w*w.w;
            w = *(const float4*)(wp + 1024); a_o  += hv.x*w.x + hv.y*w.y + hv.z*w.z + hv.w*w.w;
            w = *(const float4*)(wp + 1280); a_o  += cv.x*w.x + cv.y*w.y + cv.z*w.z + cv.w*w.w;
        }

        const float ig = sigmoidf_(a_i);
        const float fg = sigmoidf_(a_f + a_hf);
        const float og = sigmoidf_(a_o);
        const int gq = hg >> 2;
        const float curc = sc_lds[bl * 256 + ((gq ^ sb) << 2) + (hg & 3)];
        const float cg = fg * curc + ig * tanhf(xa_c + a_hf);  // w_hf reuse, per ref
        const float nh = og * tanhf(cg);

        // ---- Phase E: publish (UC) + flag ----
        const size_t wix = ((size_t)(pt + 1) * BB + bg) * HH + hg;
        st_coh(hS + wix, nh);
        st_coh(cS + wix, cg);
        out[((size_t)tB + bg) * HH + hg] = (op > 0) ? nh : prev;

        asm volatile("s_waitcnt vmcnt(0)" ::: "memory");
        __syncthreads();
        if (tid == 0)
            __hip_atomic_store(grpflags + htile * FLAG_STRIDE, (unsigned)(t + 1),
                               __ATOMIC_RELAXED, __HIP_MEMORY_SCOPE_AGENT);
    }
}

extern "C" void kernel_launch(void* const* d_in, const int* in_sizes, int n_in,
                              void* d_out, int out_size, void* d_ws, size_t ws_size,
                              hipStream_t stream) {
    const float* x   = (const float*)d_in[0];
    const int*   ops = (const int*)d_in[1];
    const float* wxi = (const float*)d_in[2];
    const float* bi  = (const float*)d_in[3];
    const float* whi = (const float*)d_in[4];
    const float* wci = (const float*)d_in[5];
    const float* wxf = (const float*)d_in[6];
    const float* bf  = (const float*)d_in[7];
    const float* whf = (const float*)d_in[8];
    const float* wcf = (const float*)d_in[9];
    const float* wxc = (const float*)d_in[10];
    const float* bc  = (const float*)d_in[11];
    const float* wxo = (const float*)d_in[12];
    const float* bo  = (const float*)d_in[13];
    const float* who = (const float*)d_in[14];
    const float* wco = (const float*)d_in[15];
    const float* h0  = (const float*)d_in[16];
    const float* c0  = (const float*)d_in[17];
    float* out = (float*)d_out;

    const size_t stackElems = (size_t)SP1 * BB * HH;   // 8,454,144 floats
    const size_t flagElems  = (size_t)256 * FLAG_STRIDE;
    float*    hS    = (float*)d_ws;
    float*    cS    = hS + stackElems;
    int*      pts   = (int*)(cS + stackElems);
    unsigned* flags = (unsigned*)(pts + (size_t)TT * BB);
    size_t need = (size_t)((char*)(flags + flagElems) - (char*)d_ws);
    if (ws_size < need) return;

    hipFuncSetAttribute((const void*)k_main,
                        hipFuncAttributeMaxDynamicSharedMemorySize, 163840);

    hipMemsetAsync((void*)flags, 0, flagElems * sizeof(unsigned), stream);
    k_pts<<<1, 256, 0, stream>>>(ops, pts);
    k_init<<<BB, HH, 0, stream>>>(h0, c0, hS, cS);
    k_main<<<NBLK, 256, 163840, stream>>>(x, ops, wxi, bi, whi, wci, wxf, bf, whf, wcf,
                                          wxc, bc, wxo, bo, who, wco,
                                          hS, cS, pts, flags, out);
}